// Round 19
// baseline (573.171 us; speedup 1.0000x reference)
//
#include <hip/hip_runtime.h>
#include <hip/hip_bf16.h>

typedef __attribute__((ext_vector_type(8))) short short8;
typedef __attribute__((ext_vector_type(4))) float f32x4;

#define TWARM 96
#define SOUT  24
#define WIN   24   // x staging window (timesteps per per-wave LDS window)
#define XPS   25   // padded x_lds row stride in words (kills bank aliasing)
#define NWIN  (TWARM / WIN)
#define K1 1.44269504089f   // log2(e)
#define K2 2.88539008178f   // 2*log2(e)

// Per-step fence: s_waitcnt + memory clobber pins ALL memory ops (bounded
// live ranges — r14's explosion is impossible) but, unlike r10-r17, NO
// sched_barrier: VALU/MFMA may flow across the step boundary to fill the
// fence-latency bubbles (~30% of wall at the measured VALU-issue floor).
#define LGKM_FENCE() do { \
    asm volatile("s_waitcnt lgkmcnt(0)" ::: "memory"); \
} while (0)

static __device__ __forceinline__ short f2bf(float f) {
    __hip_bfloat16 h = __float2bfloat16(f);
    return *reinterpret_cast<short*>(&h);
}
static __device__ __forceinline__ float bf2f(short s) {
    unsigned u = ((unsigned)(unsigned short)s) << 16;
    return __builtin_bit_cast(float, u);
}
static __device__ __forceinline__ unsigned pkbf(float lo, float hi) {
    return (unsigned)(unsigned short)f2bf(lo)
         | ((unsigned)(unsigned short)f2bf(hi) << 16);
}

// r17 base (best: x@W+b on the MFMA pipe via K-extension, compact frag-2,
// 8 waves/block sharing one U copy, 2 blocks/CU = 16 waves/CU) + two cuts:
// (1) fence without sched_barrier (fill VALU bubbles across steps);
// (2) 8 of 16 loop-invariant u2 fragments hoisted to registers (32 VGPR,
//     total ~96 < 128 budget) — 8 fewer LDS reads/step.
__global__ void __attribute__((amdgpu_flat_work_group_size(512, 512),
                               amdgpu_waves_per_eu(4, 4)))
lstm_ar_kernel(const float* __restrict__ gin, const float* __restrict__ gW,
               const float* __restrict__ gU, const float* __restrict__ gb,
               const float* __restrict__ gWd, const float* __restrict__ gbd,
               float* __restrict__ gout, int B)
{
    __shared__ __align__(16) short    U_lds[16384];        // 32 KB: frag 0,1 (H@U)
    __shared__ __align__(16) short    U2_lds[2048];        // 4 KB: compact frag 2
    __shared__ __align__(16) short    h_lds[8][16][72];    // 18 KB, per-wave padded
    __shared__ __align__(16) unsigned x_lds[8][16][XPS];   // 12.5 KB bf16-pair x / preds
    __shared__ float wdc_lds[4][2][16];                    // 512 B

    const int tid  = threadIdx.x;
    const int wv   = tid >> 6;
    const int lane = tid & 63;
    const int c4   = lane & 15;   // MFMA col / A-row selector
    const int hi   = lane >> 4;   // MFMA k-group / C-row group

    // ---- stage U fragments 0,1 (H@U part; swizzled, gate-scale folded) ----
    for (int idx = tid; idx < 16384; idx += 512) {
        int k = idx >> 8, col = idx & 255;
        float sc = ((col >> 6) == 2) ? -K2 : -K1;   // g columns get -2*log2e
        int n = col >> 4, frag = k >> 5, sub = (k & 31) >> 3;
        int dst = (n * 2 + frag) * 512 + sub * 128 + (col & 15) * 8 + (k & 7);
        U_lds[dst] = f2bf(sc * gU[idx]);
    }
    // ---- stage compact U fragment 2: k_v 0->W0, 1->W1, 2->b, 3..7 -> 0 ----
    for (int i = tid; i < 2048; i += 512) {
        int n = i >> 7, cc = (i >> 3) & 15, e = i & 7;
        int col = n * 16 + cc;
        float sc = ((col >> 6) == 2) ? -K2 : -K1;
        float v = 0.f;
        if (e == 0)      v = sc * gW[col];
        else if (e == 1) v = sc * gW[256 + col];
        else if (e == 2) v = sc * gb[col];
        U2_lds[n * 128 + cc * 8 + e] = f2bf(v);
    }
    // ---- Wd table ----
    if (tid < 128) {
        int tt = tid >> 5, j = (tid >> 4) & 1, cc = tid & 15;
        wdc_lds[tt][j][cc] = gWd[(tt * 16 + cc) * 2 + j];
    }
    const float bd0 = gbd[0], bd1 = gbd[1];

    const int row0   = blockIdx.x * 128 + wv * 16;
    const bool active = (row0 + 15) < B;

    // zero this wave's h buffer
    for (int i = lane; i < 16 * 72; i += 64) (&h_lds[wv][0][0])[i] = 0;

    // ---- per-wave x window staging: 16 rows x WIN steps, bf16 pairs ----
    const int xrow = lane >> 2, xq = lane & 3;   // 4 lanes/row, 12 floats each
    auto stage_x = [&](int w) {
        const float* src = gin + (size_t)(row0 + xrow) * (TWARM * 2)
                         + w * (WIN * 2) + xq * 12;
#pragma unroll
        for (int m = 0; m < 3; ++m) {
            float4 v = *reinterpret_cast<const float4*>(src + m * 4);
            x_lds[wv][xrow][xq * 6 + m * 2 + 0] = pkbf(v.x, v.y);
            x_lds[wv][xrow][xq * 6 + m * 2 + 1] = pkbf(v.z, v.w);
        }
        LGKM_FENCE();   // window visible to this wave before first read
    };

    if (active) stage_x(0);
    __syncthreads();    // the ONLY block barrier: U + U2 + wdc staged & visible
    if (!active) return;

    const short* hptr  = &h_lds[wv][0][0] + c4 * 72 + hi * 8;     // A-frag read base
    short*       hwptr = &h_lds[wv][0][0] + (hi * 4) * 72 + c4;   // h write base
    const short* uptr  = U_lds + lane * 8;                        // B-frag read base
    const short* uptr2 = U2_lds + c4 * 8;        // compact frag 2 (hi groups broadcast)

    // hoist the first 8 loop-invariant u2 fragments (tiles n=0..7) to regs
    short8 u2r[8];
#pragma unroll
    for (int n = 0; n < 8; ++n)
        u2r[n] = *reinterpret_cast<const short8*>(uptr2 + n * 128);

    float c_[4][4];     // pre-scaled: c' = -K2 * c
#pragma unroll
    for (int tt = 0; tt < 4; ++tt)
#pragma unroll
        for (int r = 0; r < 4; ++r) c_[tt][r] = 0.f;

    const f32x4 zero4 = {0.f, 0.f, 0.f, 0.f};   // loop-invariant MFMA C-init
    float h_[4][4];     // live during decode only

    // ---- one LSTM step; acc is z' = -K*z; four gate-group quarters.
    //      xp = bf16-packed (x0,x1) for row c4 (any value for hi!=0 lanes). ----
    auto lstm_step = [&](unsigned xp, bool save_h) {
        short8 a0v = *reinterpret_cast<const short8*>(hptr);
        short8 a1v = *reinterpret_cast<const short8*>(hptr + 32);
        short8 a2v = {0, 0, 0, 0, 0, 0, 0, 0};   // virtual K-rows {x0, x1, 1}
        if (hi == 0) {
            a2v[0] = (short)(xp & 0xFFFFu);
            a2v[1] = (short)(xp >> 16);
            a2v[2] = (short)0x3F80;              // bf16(1.0) multiplies b
        }
#pragma unroll
        for (int tt = 0; tt < 4; ++tt) {
            f32x4 acc[4];   // tiles n = tt, tt+4, tt+8, tt+12 -> i,f,g,o
#pragma unroll
            for (int j = 0; j < 4; ++j) {
                const int n = tt + 4 * j;
                // tiles 0..7 from registers; 8..15 from LDS (broadcast read)
                short8 u2 = (n < 8)
                    ? u2r[n]
                    : *reinterpret_cast<const short8*>(uptr2 + n * 128);
                acc[j] = __builtin_amdgcn_mfma_f32_16x16x32_bf16(a2v, u2, zero4, 0, 0, 0);
            }
#pragma unroll
            for (int j = 0; j < 4; ++j) {
                const int n = tt + 4 * j;
                short8 u0 = *reinterpret_cast<const short8*>(uptr + (n * 2 + 0) * 512);
                short8 u1 = *reinterpret_cast<const short8*>(uptr + (n * 2 + 1) * 512);
                acc[j] = __builtin_amdgcn_mfma_f32_16x16x32_bf16(a0v, u0, acc[j], 0, 0, 0);
                acc[j] = __builtin_amdgcn_mfma_f32_16x16x32_bf16(a1v, u1, acc[j], 0, 0, 0);
            }
            // ea=e^{-zi}, ef=e^{-zf}, eg=e^{-2zg}, eo=e^{-zo}
            // c' update: c'n = sf*c' + (K2*eg - K2)*rcp((1+ea)(1+eg)); ec = exp2(c'n)
#pragma unroll
            for (int r = 0; r < 4; ++r) {
                float ea = __builtin_amdgcn_exp2f(acc[0][r]);
                float ef = __builtin_amdgcn_exp2f(acc[1][r]);
                float eg = __builtin_amdgcn_exp2f(acc[2][r]);
                float eo = __builtin_amdgcn_exp2f(acc[3][r]);
                float sf = __builtin_amdgcn_rcpf(1.0f + ef);
                float sg = fmaf(eg, K2, -K2) *
                    __builtin_amdgcn_rcpf((1.0f + ea) * (1.0f + eg));
                float cn = fmaf(sf, c_[tt][r], sg);
                c_[tt][r] = cn;
                float ec = __builtin_amdgcn_exp2f(cn);
                float hn = (1.0f - ec) *
                    __builtin_amdgcn_rcpf((1.0f + eo) * (1.0f + ec));
                if (save_h) h_[tt][r] = hn;
                hwptr[r * 72 + tt * 16] = f2bf(hn);
            }
        }
        LGKM_FENCE();   // h writes ordered before next step's A-frag reads
    };

    // ---- warmup: 96 steps, x from this wave's LDS windows (1 read/step) ----
#pragma unroll 1
    for (int w = 0; w < NWIN; ++w) {
        if (w != 0) stage_x(w);   // prior step's fence ordered old-window reads
#pragma unroll 1
        for (int tl = 0; tl < WIN; ++tl)
            lstm_step(x_lds[wv][c4][tl], false);
    }

    // rebuild h_ (f32) from the bf16 LDS copy once after warmup
#pragma unroll
    for (int tt = 0; tt < 4; ++tt)
#pragma unroll
        for (int r = 0; r < 4; ++r)
            h_[tt][r] = bf2f((&h_lds[wv][0][0])[(hi * 4 + r) * 72 + tt * 16 + c4]);

    // hoist Wd for this lane's cols (decode-only registers)
    float wdc[4][2];
#pragma unroll
    for (int tt = 0; tt < 4; ++tt) {
        wdc[tt][0] = wdc_lds[tt][0][c4];
        wdc[tt][1] = wdc_lds[tt][1][c4];
    }

    // ---- decode: pred = h@Wd + bd, butterfly over the 16-lane col group ----
    auto make_pred = [&](float* p0, float* p1) {
#pragma unroll
        for (int r = 0; r < 4; ++r) {
            float a0 = 0.f, a1 = 0.f;
#pragma unroll
            for (int tt = 0; tt < 4; ++tt) {
                a0 = fmaf(h_[tt][r], wdc[tt][0], a0);
                a1 = fmaf(h_[tt][r], wdc[tt][1], a1);
            }
            p0[r] = a0; p1[r] = a1;
        }
#pragma unroll
        for (int m = 1; m < 16; m <<= 1)
#pragma unroll
            for (int r = 0; r < 4; ++r) {
                p0[r] += __shfl_xor(p0[r], m, 64);
                p1[r] += __shfl_xor(p1[r], m, 64);
            }
#pragma unroll
        for (int r = 0; r < 4; ++r) { p0[r] += bd0; p1[r] += bd1; }
    };
    // fetch row c4's pred from the lane group that owns it; pack bf16 pair
    auto build_xp = [&](const float* p0, const float* p1) -> unsigned {
        int srcl = (c4 >> 2) << 4;   // lane with hi = c4>>2 (col 0 of its group)
        float a  = __shfl(p0[0], srcl, 64), b2 = __shfl(p0[1], srcl, 64);
        float cc = __shfl(p0[2], srcl, 64), d  = __shfl(p0[3], srcl, 64);
        float e  = __shfl(p1[0], srcl, 64), f  = __shfl(p1[1], srcl, 64);
        float g  = __shfl(p1[2], srcl, 64), h2 = __shfl(p1[3], srcl, 64);
        int rr = c4 & 3;
        float q0 = (rr & 2) ? ((rr & 1) ? d  : cc) : ((rr & 1) ? b2 : a);
        float q1 = (rr & 2) ? ((rr & 1) ? h2 : g)  : ((rr & 1) ? f  : e);
        return pkbf(q0, q1);
    };
    // stash pred bf16 in this wave's (dead) x window for the final writeout
    auto store_pred = [&](int s, const float* p0, const float* p1) {
        if (c4 == 0) {
#pragma unroll
            for (int r = 0; r < 4; ++r)
                x_lds[wv][hi * 4 + r][s] = pkbf(p0[r], p1[r]);
        }
    };

    float p0[4], p1[4];
    make_pred(p0, p1);
    store_pred(0, p0, p1);
#pragma unroll 1
    for (int s = 1; s < SOUT; ++s) {
        lstm_step(build_xp(p0, p1), true);
        make_pred(p0, p1);
        store_pred(s, p0, p1);
    }
    LGKM_FENCE();   // all pred stashes of this wave visible to this wave

    // ---- per-wave coalesced writeout: 16 rows x 48 floats ----
#pragma unroll
    for (int m = 0; m < 6; ++m) {
        unsigned u = x_lds[wv][xrow][xq * 6 + m];
        *reinterpret_cast<float2*>(
            gout + (size_t)(row0 + xrow) * (SOUT * 2) + xq * 12 + m * 2) =
            make_float2(bf2f((short)(u & 0xFFFFu)), bf2f((short)(u >> 16)));
    }
}

extern "C" void kernel_launch(void* const* d_in, const int* in_sizes, int n_in,
                              void* d_out, int out_size, void* d_ws, size_t ws_size,
                              hipStream_t stream) {
    const float* gin  = (const float*)d_in[0];
    const float* gW   = (const float*)d_in[1];
    const float* gU   = (const float*)d_in[2];
    const float* gb   = (const float*)d_in[3];
    const float* gWd  = (const float*)d_in[4];
    const float* gbd  = (const float*)d_in[5];
    float* gout = (float*)d_out;

    const int B = in_sizes[0] / (TWARM * 2);
    const int blocks = (B + 127) / 128;
    lstm_ar_kernel<<<blocks, 512, 0, stream>>>(gin, gW, gU, gb, gWd, gbd, gout, B);
}

// Round 20
// 547.467 us; speedup vs baseline: 1.0470x; 1.0470x over previous
//
#include <hip/hip_runtime.h>
#include <hip/hip_bf16.h>

typedef __attribute__((ext_vector_type(8))) short short8;
typedef __attribute__((ext_vector_type(4))) float f32x4;

#define TWARM 96
#define SOUT  24
#define WIN   24   // x staging window (timesteps per per-wave LDS window)
#define XPS   25   // padded x_lds row stride in words (kills bank aliasing)
#define NWIN  (TWARM / WIN)
#define K1 1.44269504089f   // log2(e)
#define K2 2.88539008178f   // 2*log2(e)

// Intra-wave fence: LDS ordering AND (r14 lesson) a scheduler region boundary
// that stops cross-step hoisting from exploding live ranges. (r19 lesson:
// the "memory" clobber also defeats cross-step register caching of LDS data —
// accepted cost; removing it regressed 6x in r14.)
#define LGKM_FENCE() do { \
    asm volatile("s_waitcnt lgkmcnt(0)" ::: "memory"); \
    __builtin_amdgcn_sched_barrier(0); \
} while (0)

static __device__ __forceinline__ short f2bf(float f) {
    __hip_bfloat16 h = __float2bfloat16(f);
    return *reinterpret_cast<short*>(&h);
}
static __device__ __forceinline__ float bf2f(short s) {
    unsigned u = ((unsigned)(unsigned short)s) << 16;
    return __builtin_bit_cast(float, u);
}
static __device__ __forceinline__ unsigned pkbf(float lo, float hi) {
    return (unsigned)(unsigned short)f2bf(lo)
         | ((unsigned)(unsigned short)f2bf(hi) << 16);
}

// Exact r17 base (best: 544 us — x@W+b on the MFMA pipe via K-extension,
// compact frag-2, 8 waves/block sharing one U copy, 16 waves/CU, spill-free
// at VGPR=64) + ONE change: the f-gate reciprocal and the ig-product
// reciprocal share a single v_rcp via R = rcp(A*B): sf = R*A, 1/A = R*B.
// Per element: 5 exp2 + 2 rcp (was 3 rcp) — a ~12% cut of the binding
// trans-pipe issue load. (Third rcp can't merge: ec depends on sf.)
__global__ void __attribute__((amdgpu_flat_work_group_size(512, 512),
                               amdgpu_waves_per_eu(4, 4)))
lstm_ar_kernel(const float* __restrict__ gin, const float* __restrict__ gW,
               const float* __restrict__ gU, const float* __restrict__ gb,
               const float* __restrict__ gWd, const float* __restrict__ gbd,
               float* __restrict__ gout, int B)
{
    __shared__ __align__(16) short    U_lds[16384];        // 32 KB: frag 0,1 (H@U)
    __shared__ __align__(16) short    U2_lds[2048];        // 4 KB: compact frag 2
    __shared__ __align__(16) short    h_lds[8][16][72];    // 18 KB, per-wave padded
    __shared__ __align__(16) unsigned x_lds[8][16][XPS];   // 12.5 KB bf16-pair x / preds
    __shared__ float wdc_lds[4][2][16];                    // 512 B

    const int tid  = threadIdx.x;
    const int wv   = tid >> 6;
    const int lane = tid & 63;
    const int c4   = lane & 15;   // MFMA col / A-row selector
    const int hi   = lane >> 4;   // MFMA k-group / C-row group

    // ---- stage U fragments 0,1 (H@U part; swizzled, gate-scale folded) ----
    for (int idx = tid; idx < 16384; idx += 512) {
        int k = idx >> 8, col = idx & 255;
        float sc = ((col >> 6) == 2) ? -K2 : -K1;   // g columns get -2*log2e
        int n = col >> 4, frag = k >> 5, sub = (k & 31) >> 3;
        int dst = (n * 2 + frag) * 512 + sub * 128 + (col & 15) * 8 + (k & 7);
        U_lds[dst] = f2bf(sc * gU[idx]);
    }
    // ---- stage compact U fragment 2: k_v 0->W0, 1->W1, 2->b, 3..7 -> 0 ----
    for (int i = tid; i < 2048; i += 512) {
        int n = i >> 7, cc = (i >> 3) & 15, e = i & 7;
        int col = n * 16 + cc;
        float sc = ((col >> 6) == 2) ? -K2 : -K1;
        float v = 0.f;
        if (e == 0)      v = sc * gW[col];
        else if (e == 1) v = sc * gW[256 + col];
        else if (e == 2) v = sc * gb[col];
        U2_lds[n * 128 + cc * 8 + e] = f2bf(v);
    }
    // ---- Wd table ----
    if (tid < 128) {
        int tt = tid >> 5, j = (tid >> 4) & 1, cc = tid & 15;
        wdc_lds[tt][j][cc] = gWd[(tt * 16 + cc) * 2 + j];
    }
    const float bd0 = gbd[0], bd1 = gbd[1];

    const int row0   = blockIdx.x * 128 + wv * 16;
    const bool active = (row0 + 15) < B;

    // zero this wave's h buffer
    for (int i = lane; i < 16 * 72; i += 64) (&h_lds[wv][0][0])[i] = 0;

    // ---- per-wave x window staging: 16 rows x WIN steps, bf16 pairs ----
    const int xrow = lane >> 2, xq = lane & 3;   // 4 lanes/row, 12 floats each
    auto stage_x = [&](int w) {
        const float* src = gin + (size_t)(row0 + xrow) * (TWARM * 2)
                         + w * (WIN * 2) + xq * 12;
#pragma unroll
        for (int m = 0; m < 3; ++m) {
            float4 v = *reinterpret_cast<const float4*>(src + m * 4);
            x_lds[wv][xrow][xq * 6 + m * 2 + 0] = pkbf(v.x, v.y);
            x_lds[wv][xrow][xq * 6 + m * 2 + 1] = pkbf(v.z, v.w);
        }
        LGKM_FENCE();   // window visible to this wave before first read
    };

    if (active) stage_x(0);
    __syncthreads();    // the ONLY block barrier: U + U2 + wdc staged & visible
    if (!active) return;

    float c_[4][4];     // pre-scaled: c' = -K2 * c
#pragma unroll
    for (int tt = 0; tt < 4; ++tt)
#pragma unroll
        for (int r = 0; r < 4; ++r) c_[tt][r] = 0.f;

    const short* hptr  = &h_lds[wv][0][0] + c4 * 72 + hi * 8;     // A-frag read base
    short*       hwptr = &h_lds[wv][0][0] + (hi * 4) * 72 + c4;   // h write base
    const short* uptr  = U_lds + lane * 8;                        // B-frag read base
    const short* uptr2 = U2_lds + c4 * 8;        // compact frag 2 (hi groups broadcast)

    const f32x4 zero4 = {0.f, 0.f, 0.f, 0.f};   // loop-invariant MFMA C-init
    float h_[4][4];     // live during decode only

    // ---- one LSTM step; acc is z' = -K*z; four gate-group quarters.
    //      xp = bf16-packed (x0,x1) for row c4 (any value for hi!=0 lanes). ----
    auto lstm_step = [&](unsigned xp, bool save_h) {
        short8 a0v = *reinterpret_cast<const short8*>(hptr);
        short8 a1v = *reinterpret_cast<const short8*>(hptr + 32);
        short8 a2v = {0, 0, 0, 0, 0, 0, 0, 0};   // virtual K-rows {x0, x1, 1}
        if (hi == 0) {
            a2v[0] = (short)(xp & 0xFFFFu);
            a2v[1] = (short)(xp >> 16);
            a2v[2] = (short)0x3F80;              // bf16(1.0) multiplies b
        }
#pragma unroll
        for (int tt = 0; tt < 4; ++tt) {
            f32x4 acc[4];   // tiles n = tt, tt+4, tt+8, tt+12 -> i,f,g,o
#pragma unroll
            for (int j = 0; j < 4; ++j) {
                const int n = tt + 4 * j;
                // compact frag 2: lanes with hi!=0 read duplicate rows — their
                // A rows are zero, so the values are don't-care.
                short8 u2 = *reinterpret_cast<const short8*>(uptr2 + n * 128);
                acc[j] = __builtin_amdgcn_mfma_f32_16x16x32_bf16(a2v, u2, zero4, 0, 0, 0);
            }
#pragma unroll
            for (int j = 0; j < 4; ++j) {
                const int n = tt + 4 * j;
                short8 u0 = *reinterpret_cast<const short8*>(uptr + (n * 2 + 0) * 512);
                short8 u1 = *reinterpret_cast<const short8*>(uptr + (n * 2 + 1) * 512);
                acc[j] = __builtin_amdgcn_mfma_f32_16x16x32_bf16(a0v, u0, acc[j], 0, 0, 0);
                acc[j] = __builtin_amdgcn_mfma_f32_16x16x32_bf16(a1v, u1, acc[j], 0, 0, 0);
            }
            // ea=e^{-zi}, ef=e^{-zf}, eg=e^{-2zg}, eo=e^{-zo}
            // MERGED rcp: R = 1/(A*Bv), A=(1+ea)(1+eg), Bv=1+ef
            //   sf = R*A = sigma(f);  sg = K2(eg-1) * (R*Bv) = K2(eg-1)/A
            // c' update: cn = sf*c' + sg; ec = exp2(cn)
#pragma unroll
            for (int r = 0; r < 4; ++r) {
                float ea = __builtin_amdgcn_exp2f(acc[0][r]);
                float ef = __builtin_amdgcn_exp2f(acc[1][r]);
                float eg = __builtin_amdgcn_exp2f(acc[2][r]);
                float eo = __builtin_amdgcn_exp2f(acc[3][r]);
                float A  = (1.0f + ea) * (1.0f + eg);
                float Bv = 1.0f + ef;
                float R  = __builtin_amdgcn_rcpf(A * Bv);
                float sf = R * A;
                float sg = fmaf(eg, K2, -K2) * (R * Bv);
                float cn = fmaf(sf, c_[tt][r], sg);
                c_[tt][r] = cn;
                float ec = __builtin_amdgcn_exp2f(cn);
                float hn = (1.0f - ec) *
                    __builtin_amdgcn_rcpf((1.0f + eo) * (1.0f + ec));
                if (save_h) h_[tt][r] = hn;
                hwptr[r * 72 + tt * 16] = f2bf(hn);
            }
        }
        LGKM_FENCE();   // h writes ordered before next step + sched region cap
    };

    // ---- warmup: 96 steps, x from this wave's LDS windows (1 read/step) ----
#pragma unroll 1
    for (int w = 0; w < NWIN; ++w) {
        if (w != 0) stage_x(w);   // prior step's fence ordered old-window reads
#pragma unroll 1
        for (int tl = 0; tl < WIN; ++tl)
            lstm_step(x_lds[wv][c4][tl], false);
    }

    // rebuild h_ (f32) from the bf16 LDS copy once after warmup
#pragma unroll
    for (int tt = 0; tt < 4; ++tt)
#pragma unroll
        for (int r = 0; r < 4; ++r)
            h_[tt][r] = bf2f((&h_lds[wv][0][0])[(hi * 4 + r) * 72 + tt * 16 + c4]);

    // hoist Wd for this lane's cols (decode-only registers)
    float wdc[4][2];
#pragma unroll
    for (int tt = 0; tt < 4; ++tt) {
        wdc[tt][0] = wdc_lds[tt][0][c4];
        wdc[tt][1] = wdc_lds[tt][1][c4];
    }

    // ---- decode: pred = h@Wd + bd, butterfly over the 16-lane col group ----
    auto make_pred = [&](float* p0, float* p1) {
#pragma unroll
        for (int r = 0; r < 4; ++r) {
            float a0 = 0.f, a1 = 0.f;
#pragma unroll
            for (int tt = 0; tt < 4; ++tt) {
                a0 = fmaf(h_[tt][r], wdc[tt][0], a0);
                a1 = fmaf(h_[tt][r], wdc[tt][1], a1);
            }
            p0[r] = a0; p1[r] = a1;
        }
#pragma unroll
        for (int m = 1; m < 16; m <<= 1)
#pragma unroll
            for (int r = 0; r < 4; ++r) {
                p0[r] += __shfl_xor(p0[r], m, 64);
                p1[r] += __shfl_xor(p1[r], m, 64);
            }
#pragma unroll
        for (int r = 0; r < 4; ++r) { p0[r] += bd0; p1[r] += bd1; }
    };
    // fetch row c4's pred from the lane group that owns it; pack bf16 pair
    auto build_xp = [&](const float* p0, const float* p1) -> unsigned {
        int srcl = (c4 >> 2) << 4;   // lane with hi = c4>>2 (col 0 of its group)
        float a  = __shfl(p0[0], srcl, 64), b2 = __shfl(p0[1], srcl, 64);
        float cc = __shfl(p0[2], srcl, 64), d  = __shfl(p0[3], srcl, 64);
        float e  = __shfl(p1[0], srcl, 64), f  = __shfl(p1[1], srcl, 64);
        float g  = __shfl(p1[2], srcl, 64), h2 = __shfl(p1[3], srcl, 64);
        int rr = c4 & 3;
        float q0 = (rr & 2) ? ((rr & 1) ? d  : cc) : ((rr & 1) ? b2 : a);
        float q1 = (rr & 2) ? ((rr & 1) ? h2 : g)  : ((rr & 1) ? f  : e);
        return pkbf(q0, q1);
    };
    // stash pred bf16 in this wave's (dead) x window for the final writeout
    auto store_pred = [&](int s, const float* p0, const float* p1) {
        if (c4 == 0) {
#pragma unroll
            for (int r = 0; r < 4; ++r)
                x_lds[wv][hi * 4 + r][s] = pkbf(p0[r], p1[r]);
        }
    };

    float p0[4], p1[4];
    make_pred(p0, p1);
    store_pred(0, p0, p1);
#pragma unroll 1
    for (int s = 1; s < SOUT; ++s) {
        lstm_step(build_xp(p0, p1), true);
        make_pred(p0, p1);
        store_pred(s, p0, p1);
    }
    LGKM_FENCE();   // all pred stashes of this wave visible to this wave

    // ---- per-wave coalesced writeout: 16 rows x 48 floats ----
#pragma unroll
    for (int m = 0; m < 6; ++m) {
        unsigned u = x_lds[wv][xrow][xq * 6 + m];
        *reinterpret_cast<float2*>(
            gout + (size_t)(row0 + xrow) * (SOUT * 2) + xq * 12 + m * 2) =
            make_float2(bf2f((short)(u & 0xFFFFu)), bf2f((short)(u >> 16)));
    }
}

extern "C" void kernel_launch(void* const* d_in, const int* in_sizes, int n_in,
                              void* d_out, int out_size, void* d_ws, size_t ws_size,
                              hipStream_t stream) {
    const float* gin  = (const float*)d_in[0];
    const float* gW   = (const float*)d_in[1];
    const float* gU   = (const float*)d_in[2];
    const float* gb   = (const float*)d_in[3];
    const float* gWd  = (const float*)d_in[4];
    const float* gbd  = (const float*)d_in[5];
    float* gout = (float*)d_out;

    const int B = in_sizes[0] / (TWARM * 2);
    const int blocks = (B + 127) / 128;
    lstm_ar_kernel<<<blocks, 512, 0, stream>>>(gin, gW, gU, gb, gWd, gbd, gout, B);
}